// Round 8
// baseline (1194.149 us; speedup 1.0000x reference)
//
#include <hip/hip_runtime.h>

// SAGEConv x2 forward. Edges bucket-partitioned by dst (256 nodes/bucket);
// aggregation accumulates directly from the partitioned pairs into LDS fp32
// accumulators via ds_add_f32 (no CSR, no fine binning, no float global
// atomics). gemm1 (fused with bucket histogram) + gemm2 on MFMA bf16.

constexpr int IN_DIM  = 128;
constexpr int HID     = 64;
constexpr int OUT_DIM = 32;
constexpr float SLOPE = 0.1f;
constexpr int NPB_SHIFT = 8;     // 256 nodes per bucket
constexpr int NBMAX = 512;       // max buckets (N <= 131072)
constexpr int CHUNK = 4096;      // edges per partition block
constexpr int HIST_BLOCKS = 256;

typedef unsigned int uint32;
typedef unsigned short ushort16;

__device__ inline float blo(uint32 u) { return __uint_as_float(u << 16); }
__device__ inline float bhi(uint32 u) { return __uint_as_float(u & 0xffff0000u); }
__device__ inline ushort16 f2b(float f) {
    uint32 u = __float_as_uint(f);
    u += 0x7fffu + ((u >> 16) & 1u);   // round-to-nearest-even
    return (ushort16)(u >> 16);
}
__device__ inline uint32 pack2(float lo, float hi) {
    return (uint32)f2b(lo) | ((uint32)f2b(hi) << 16);
}
__device__ inline float lrelu(float v) { return (v > 0.f) ? v : SLOPE * v; }

// ---- fused: MFMA gemm1 (blocks < ngemm) + bucket histogram (rest) ----
// gemm1: x[N,128] @ [Wl1|Wr1] -> xl bf16[N,64], xr fp32[N,64]+b1
__global__ __launch_bounds__(256) void gemm1_hist_kernel(
    const float* __restrict__ x, const float* __restrict__ Wl,
    const float* __restrict__ Wr, const float* __restrict__ b1,
    const int* __restrict__ dst, int* __restrict__ bhist,
    ushort16* __restrict__ xl, float* __restrict__ xr,
    int N, int E, int ngemm) {
    using frag = __attribute__((ext_vector_type(8))) short;
    using f32x4 = __attribute__((ext_vector_type(4))) float;
    constexpr int LDA = IN_DIM + 8;
    __shared__ ushort16 AB[(64 + 128) * LDA];   // 52.2 KB, shared by both paths
    const int tid = threadIdx.x;
    if (blockIdx.x >= ngemm) {                   // ---- histogram path ----
        int* bh = (int*)AB;
        for (int i = tid; i < NBMAX; i += 256) bh[i] = 0;
        __syncthreads();
        const int b0 = blockIdx.x - ngemm;
        for (int e = b0 * 256 + tid; e < E; e += HIST_BLOCKS * 256)
            atomicAdd(&bh[dst[e] >> NPB_SHIFT], 1);
        __syncthreads();
        for (int b = tid; b < NBMAX; b += 256)
            if (bh[b]) atomicAdd(&bhist[b], bh[b]);
        return;
    }
    // ---- gemm path ----
    ushort16 (*Ash)[LDA] = (ushort16(*)[LDA])AB;
    ushort16 (*Bsh)[LDA] = (ushort16(*)[LDA])(AB + 64 * LDA);
    const int n0 = blockIdx.x * 64;
    {
        const int c = tid & 63;
        for (int k = tid >> 6; k < IN_DIM; k += 4) {
            Bsh[c][k]      = f2b(Wl[k * HID + c]);
            Bsh[c + 64][k] = f2b(Wr[k * HID + c]);
        }
    }
    {
        const int lc = (tid & 31) * 4;
        for (int row = tid >> 5; row < 64; row += 8) {
            int node = n0 + row;
            float4 xv = (node < N)
                ? *reinterpret_cast<const float4*>(&x[(long)node * IN_DIM + lc])
                : float4{0.f, 0.f, 0.f, 0.f};
            ushort16 pk[4] = {f2b(xv.x), f2b(xv.y), f2b(xv.z), f2b(xv.w)};
            *reinterpret_cast<ushort2*>(&Ash[row][lc])     = ushort2{pk[0], pk[1]};
            *reinterpret_cast<ushort2*>(&Ash[row][lc + 2]) = ushort2{pk[2], pk[3]};
        }
    }
    __syncthreads();
    const int lane = tid & 63;
    const int m0   = (tid >> 6) * 16;
    const int mlo  = lane & 15;
    const int qk   = lane >> 4;
    frag Af[4];
#pragma unroll
    for (int kc = 0; kc < 4; ++kc)
        Af[kc] = *reinterpret_cast<const frag*>(&Ash[m0 + mlo][kc * 32 + qk * 8]);
#pragma unroll
    for (int ct = 0; ct < 8; ++ct) {
        f32x4 acc = {0.f, 0.f, 0.f, 0.f};
#pragma unroll
        for (int kc = 0; kc < 4; ++kc) {
            frag Bf = *reinterpret_cast<const frag*>(&Bsh[ct * 16 + mlo][kc * 32 + qk * 8]);
            acc = __builtin_amdgcn_mfma_f32_16x16x32_bf16(Af[kc], Bf, acc, 0, 0, 0);
        }
        const int col = ct * 16 + mlo;
#pragma unroll
        for (int r = 0; r < 4; ++r) {
            int node = n0 + m0 + qk * 4 + r;
            if (node < N) {
                if (col < HID) xl[(long)node * HID + col] = f2b(acc[r]);
                else           xr[(long)node * HID + (col - HID)] = acc[r] + b1[col - HID];
            }
        }
    }
}

// ---- scan bucket sizes -> padded pair bases (1 block) ----
__global__ __launch_bounds__(512) void bucket_scan_kernel(
    const int* __restrict__ bhist, int* __restrict__ pbase,
    int* __restrict__ bcur, int NB) {
    __shared__ int s2[512];
    const int t = threadIdx.x;
    int bh = (t < NB) ? bhist[t] : 0;
    int pd = (bh + 15) & ~15;
    s2[t] = pd; __syncthreads();
    for (int off = 1; off < 512; off <<= 1) {
        int b = (t >= off) ? s2[t - off] : 0;
        __syncthreads();
        s2[t] += b;
        __syncthreads();
    }
    pbase[t] = s2[t] - pd;
    bcur[t]  = s2[t] - pd;
}

// ---- partition edges into bucket regions of pairs[] ----
__global__ __launch_bounds__(256) void partition_kernel(
    const int* __restrict__ src, const int* __restrict__ dst,
    int* __restrict__ bcur, uint32* __restrict__ pairs, int E, int NB) {
    __shared__ int hist[NBMAX], loff[NBMAX], cur[NBMAX];
    __shared__ int s[256];
    __shared__ uint32 stage[CHUNK];
    const int tid = threadIdx.x;
    const int e0  = blockIdx.x * CHUNK;
    const int cnt = min(CHUNK, E - e0);
    for (int i = tid; i < NBMAX; i += 256) hist[i] = 0;
    __syncthreads();
    int sreg[16], dreg[16];
#pragma unroll
    for (int k = 0; k < 16; ++k) {
        int i = tid + k * 256;
        if (i < cnt) {
            sreg[k] = src[e0 + i];
            dreg[k] = dst[e0 + i];
            atomicAdd(&hist[dreg[k] >> NPB_SHIFT], 1);
        }
    }
    __syncthreads();
    int a0 = hist[2 * tid], a1 = hist[2 * tid + 1];
    s[tid] = a0 + a1; __syncthreads();
    for (int off = 1; off < 256; off <<= 1) {
        int t = (tid >= off) ? s[tid - off] : 0;
        __syncthreads();
        s[tid] += t;
        __syncthreads();
    }
    int ex = s[tid] - (a0 + a1);
    loff[2 * tid] = ex;      loff[2 * tid + 1] = ex + a0;
    cur[2 * tid]  = ex;      cur[2 * tid + 1]  = ex + a0;
    __syncthreads();
#pragma unroll
    for (int k = 0; k < 16; ++k) {
        int i = tid + k * 256;
        if (i < cnt) {
            int b = dreg[k] >> NPB_SHIFT;
            int pos = atomicAdd(&cur[b], 1);
            stage[pos] = (uint32)sreg[k] | ((uint32)(dreg[k] & 255) << 24);
        }
    }
    __syncthreads();
    for (int b = tid; b < NB; b += 256) {
        int cb = hist[b];
        if (cb) {
            int g  = atomicAdd(&bcur[b], cb);
            int lb = loff[b];
            for (int k = 0; k < cb; ++k) pairs[g + k] = stage[lb + k];
        }
    }
}

// ---- agg1: h = LR(mean-gather(xl) + xr), LDS fp32 accumulate ----
// 2 blocks per bucket (feature halves of 32). acc stride 33 -> bank=(dst+f)%32.
__global__ __launch_bounds__(256) void agg1_bucket_kernel(
    const uint32* __restrict__ pairs, const int* __restrict__ bhist,
    const int* __restrict__ pbase,
    const uint4* __restrict__ xlq,   // xl row n = 8 uint4
    const float* __restrict__ xr,
    uint4* __restrict__ hq, int N) { // h row n = 8 uint4
    constexpr int STR = 33;
    __shared__ float acc[256 * STR];
    __shared__ int dcnt[256];
    const int tid  = threadIdx.x;
    const int bkt  = blockIdx.x >> 1;
    const int half = blockIdx.x & 1;
    const int n0   = bkt << NPB_SHIFT;
    const int base = pbase[bkt];
    const int sz   = bhist[bkt];
    for (int i = tid; i < 256 * STR; i += 256) acc[i] = 0.f;
    dcnt[tid] = 0;
    __syncthreads();
    for (int i = tid; i < sz; i += 256)
        atomicAdd(&dcnt[pairs[base + i] >> 24], 1);
    const int lane = tid & 63;
    const int wid  = tid >> 6;
    const int li   = lane & 3;        // feature octet within half
    const int eo   = lane >> 2;       // 0..15 edge slot
    const int qoff = half * 4 + li;   // uint4 index within xl row
    for (int j0 = wid * 128; j0 < sz; j0 += 512) {
        uint4 u[8]; int dl[8]; bool ok[8];
#pragma unroll
        for (int b = 0; b < 8; ++b) {
            int e = j0 + b * 16 + eo;
            ok[b] = e < sz;
            int ec = ok[b] ? e : (sz - 1);
            uint32 pr = pairs[base + ec];
            dl[b] = pr >> 24;
            u[b]  = xlq[(long)(pr & 0xFFFFFFu) * 8 + qoff];
        }
#pragma unroll
        for (int b = 0; b < 8; ++b) {
            if (ok[b]) {
                float* a = &acc[dl[b] * STR + li * 8];
                atomicAdd(a + 0, blo(u[b].x)); atomicAdd(a + 1, bhi(u[b].x));
                atomicAdd(a + 2, blo(u[b].y)); atomicAdd(a + 3, bhi(u[b].y));
                atomicAdd(a + 4, blo(u[b].z)); atomicAdd(a + 5, bhi(u[b].z));
                atomicAdd(a + 6, blo(u[b].w)); atomicAdd(a + 7, bhi(u[b].w));
            }
        }
    }
    __syncthreads();
    const int n = n0 + tid;
    if (n >= N) return;
    const float dinv = 1.f / fmaxf((float)dcnt[tid], 1.f);
    const float* xrp = &xr[(long)n * HID + half * 32];
#pragma unroll
    for (int q = 0; q < 4; ++q) {
        float4 xa = *reinterpret_cast<const float4*>(xrp + q * 8);
        float4 xb = *reinterpret_cast<const float4*>(xrp + q * 8 + 4);
        const float* a = &acc[tid * STR + q * 8];
        float h0 = lrelu(fmaf(a[0], dinv, xa.x));
        float h1 = lrelu(fmaf(a[1], dinv, xa.y));
        float h2 = lrelu(fmaf(a[2], dinv, xa.z));
        float h3 = lrelu(fmaf(a[3], dinv, xa.w));
        float h4 = lrelu(fmaf(a[4], dinv, xb.x));
        float h5 = lrelu(fmaf(a[5], dinv, xb.y));
        float h6 = lrelu(fmaf(a[6], dinv, xb.z));
        float h7 = lrelu(fmaf(a[7], dinv, xb.w));
        uint4 pk;
        pk.x = pack2(h0, h1); pk.y = pack2(h2, h3);
        pk.z = pack2(h4, h5); pk.w = pack2(h6, h7);
        hq[(long)n * 8 + half * 4 + q] = pk;
    }
}

// ---- MFMA gemm2: h bf16[N,64] @ [Wl2|Wr2] -> hl bf16[N,32], hr fp32[N,32]+b2
__global__ __launch_bounds__(256) void gemm2_mfma_kernel(
    const ushort16* __restrict__ hs, const float* __restrict__ Wl2,
    const float* __restrict__ Wr2, const float* __restrict__ b2,
    ushort16* __restrict__ hl, float* __restrict__ hr, int N) {
    using frag = __attribute__((ext_vector_type(8))) short;
    using f32x4 = __attribute__((ext_vector_type(4))) float;
    __shared__ ushort16 Bsh[64][72];
    const int tid = threadIdx.x;
    const int n0  = blockIdx.x * 64;
    {
        const int c = tid & 63;
        for (int k = tid >> 6; k < HID; k += 4) {
            float w = (c < OUT_DIM) ? Wl2[k * OUT_DIM + c]
                                    : Wr2[k * OUT_DIM + (c - OUT_DIM)];
            Bsh[c][k] = f2b(w);
        }
    }
    __syncthreads();
    const int lane = tid & 63;
    const int m0   = (tid >> 6) * 16;
    const int mlo  = lane & 15;
    const int qk   = lane >> 4;
    const int row  = n0 + m0 + mlo;
    const int arow = (row < N) ? row : 0;
    frag Af[2];
#pragma unroll
    for (int kc = 0; kc < 2; ++kc)
        Af[kc] = *reinterpret_cast<const frag*>(&hs[(long)arow * HID + kc * 32 + qk * 8]);
#pragma unroll
    for (int ct = 0; ct < 4; ++ct) {
        f32x4 acc = {0.f, 0.f, 0.f, 0.f};
#pragma unroll
        for (int kc = 0; kc < 2; ++kc) {
            frag Bf = *reinterpret_cast<const frag*>(&Bsh[ct * 16 + mlo][kc * 32 + qk * 8]);
            acc = __builtin_amdgcn_mfma_f32_16x16x32_bf16(Af[kc], Bf, acc, 0, 0, 0);
        }
        const int col = ct * 16 + mlo;
#pragma unroll
        for (int r = 0; r < 4; ++r) {
            int node = n0 + m0 + qk * 4 + r;
            if (node < N) {
                if (col < OUT_DIM) hl[(long)node * OUT_DIM + col] = f2b(acc[r]);
                else hr[(long)node * OUT_DIM + (col - OUT_DIM)] = acc[r] + b2[col - OUT_DIM];
            }
        }
    }
}

// ---- agg2: z = LR(mean-gather(hl) + hr), LDS fp32 accumulate ----
// 2 blocks per bucket (feature halves of 16). Sibling blocks are 8 apart
// (same XCD under round-robin) so the shared 64B hl line hits L2.
__global__ __launch_bounds__(256) void agg2_bucket_kernel(
    const uint32* __restrict__ pairs, const int* __restrict__ bhist,
    const int* __restrict__ pbase,
    const uint4* __restrict__ hlq,   // hl row n = 4 uint4
    const float* __restrict__ hr,
    float* __restrict__ z, int N, int NB) {
    constexpr int STR = 17;
    __shared__ float acc[256 * STR];
    __shared__ int dcnt[256];
    const int g    = blockIdx.x;
    const int bkt  = ((g >> 4) << 3) | (g & 7);
    const int half = (g >> 3) & 1;
    if (bkt >= NB) return;
    const int tid  = threadIdx.x;
    const int n0   = bkt << NPB_SHIFT;
    const int base = pbase[bkt];
    const int sz   = bhist[bkt];
    for (int i = tid; i < 256 * STR; i += 256) acc[i] = 0.f;
    dcnt[tid] = 0;
    __syncthreads();
    for (int i = tid; i < sz; i += 256)
        atomicAdd(&dcnt[pairs[base + i] >> 24], 1);
    const int lane = tid & 63;
    const int wid  = tid >> 6;
    const int li   = lane & 1;        // feature octet within half (2 per half)
    const int eo   = lane >> 1;       // 0..31 edge slot
    const int qoff = half * 2 + li;   // uint4 index within hl row
    for (int j0 = wid * 256; j0 < sz; j0 += 1024) {
        uint4 u[8]; int dl[8]; bool ok[8];
#pragma unroll
        for (int b = 0; b < 8; ++b) {
            int e = j0 + b * 32 + eo;
            ok[b] = e < sz;
            int ec = ok[b] ? e : (sz - 1);
            uint32 pr = pairs[base + ec];
            dl[b] = pr >> 24;
            u[b]  = hlq[(long)(pr & 0xFFFFFFu) * 4 + qoff];
        }
#pragma unroll
        for (int b = 0; b < 8; ++b) {
            if (ok[b]) {
                float* a = &acc[dl[b] * STR + li * 8];
                atomicAdd(a + 0, blo(u[b].x)); atomicAdd(a + 1, bhi(u[b].x));
                atomicAdd(a + 2, blo(u[b].y)); atomicAdd(a + 3, bhi(u[b].y));
                atomicAdd(a + 4, blo(u[b].z)); atomicAdd(a + 5, bhi(u[b].z));
                atomicAdd(a + 6, blo(u[b].w)); atomicAdd(a + 7, bhi(u[b].w));
            }
        }
    }
    __syncthreads();
    const int n = n0 + tid;
    if (n >= N) return;
    const float dinv = 1.f / fmaxf((float)dcnt[tid], 1.f);
    const float* hrp = &hr[(long)n * OUT_DIM + half * 16];
    float* zp = &z[(long)n * OUT_DIM + half * 16];
#pragma unroll
    for (int q = 0; q < 2; ++q) {
        float4 ha = *reinterpret_cast<const float4*>(hrp + q * 8);
        float4 hb = *reinterpret_cast<const float4*>(hrp + q * 8 + 4);
        const float* a = &acc[tid * STR + q * 8];
        float4 va, vb;
        va.x = lrelu(fmaf(a[0], dinv, ha.x));
        va.y = lrelu(fmaf(a[1], dinv, ha.y));
        va.z = lrelu(fmaf(a[2], dinv, ha.z));
        va.w = lrelu(fmaf(a[3], dinv, ha.w));
        vb.x = lrelu(fmaf(a[4], dinv, hb.x));
        vb.y = lrelu(fmaf(a[5], dinv, hb.y));
        vb.z = lrelu(fmaf(a[6], dinv, hb.z));
        vb.w = lrelu(fmaf(a[7], dinv, hb.w));
        *reinterpret_cast<float4*>(zp + q * 8)     = va;
        *reinterpret_cast<float4*>(zp + q * 8 + 4) = vb;
    }
}

extern "C" void kernel_launch(void* const* d_in, const int* in_sizes, int n_in,
                              void* d_out, int out_size, void* d_ws, size_t ws_size,
                              hipStream_t stream) {
    const float* x   = (const float*)d_in[0];
    const int*   ei  = (const int*)d_in[1];
    const float* Wl1 = (const float*)d_in[2];
    const float* Wr1 = (const float*)d_in[3];
    const float* b1  = (const float*)d_in[4];
    const float* Wl2 = (const float*)d_in[5];
    const float* Wr2 = (const float*)d_in[6];
    const float* b2  = (const float*)d_in[7];

    const int N = in_sizes[0] / IN_DIM;
    const int E = in_sizes[1] / 2;
    const int* src = ei;
    const int* dst = ei + E;
    const int NB = (N + 255) >> NPB_SHIFT;   // buckets (<= 512)

    char* p = (char*)d_ws;
    int* bhist    = (int*)p;           p += sizeof(int) * NBMAX;
    int* pbase    = (int*)p;           p += sizeof(int) * NBMAX;
    int* bcur     = (int*)p;           p += sizeof(int) * NBMAX;
    uint32* pairs = (uint32*)p;        p += sizeof(uint32) * ((size_t)E + 16 * NBMAX);
    ushort16* xl  = (ushort16*)p;      p += sizeof(ushort16) * (size_t)N * HID;
    float* xr     = (float*)p;         p += sizeof(float) * (size_t)N * HID;
    ushort16* h   = (ushort16*)p;      p += sizeof(ushort16) * (size_t)N * HID;
    ushort16* hl  = (ushort16*)p;      p += sizeof(ushort16) * (size_t)N * OUT_DIM;
    float* hr     = (float*)p;         p += sizeof(float) * (size_t)N * OUT_DIM;

    hipMemsetAsync(bhist, 0, sizeof(int) * NBMAX, stream);

    const int ngemm = (N + 63) / 64;
    gemm1_hist_kernel<<<ngemm + HIST_BLOCKS, 256, 0, stream>>>(
        x, Wl1, Wr1, b1, dst, bhist, xl, xr, N, E, ngemm);
    bucket_scan_kernel<<<1, 512, 0, stream>>>(bhist, pbase, bcur, NB);
    partition_kernel<<<(E + CHUNK - 1) / CHUNK, 256, 0, stream>>>(src, dst, bcur, pairs, E, NB);
    agg1_bucket_kernel<<<NB * 2, 256, 0, stream>>>(pairs, bhist, pbase,
                                                   (const uint4*)xl, xr, (uint4*)h, N);
    gemm2_mfma_kernel<<<(N + 63) / 64, 256, 0, stream>>>(h, Wl2, Wr2, b2, hl, hr, N);
    const int nagg2 = ((NB + 7) & ~7) * 2;
    agg2_bucket_kernel<<<nagg2, 256, 0, stream>>>(pairs, bhist, pbase,
                                                  (const uint4*)hl, hr, (float*)d_out, N, NB);
}

// Round 9
// 274.201 us; speedup vs baseline: 4.3550x; 4.3550x over previous
//
#include <hip/hip_runtime.h>

// SAGEConv x2 forward. Edges bucket-partitioned by dst (256 nodes/bucket).
// agg1 fuses fine-binning (LDS sort, 2 int LDS-atomics/edge — NOT the R8
// 32-float-atomics/edge disaster) with the gather, and emits CSR for agg2.
// gemm1/gemm2 on MFMA bf16 with pre-converted bf16 weights (prep kernel);
// gemm1 keeps only the A-tile in LDS, gemm2 uses no LDS.

constexpr int IN_DIM  = 128;
constexpr int HID     = 64;
constexpr int OUT_DIM = 32;
constexpr float SLOPE = 0.1f;
constexpr int NPB_SHIFT = 8;     // 256 nodes per bucket
constexpr int NBMAX = 512;       // max buckets (N <= 131072)
constexpr int CHUNK = 4096;      // edges per partition block
constexpr int HIST_BLOCKS = 256;
constexpr int SUBCAP = 4096;     // per-half-bucket edge capacity (avg ~2048)

typedef unsigned int uint32;
typedef unsigned short ushort16;

__device__ inline float blo(uint32 u) { return __uint_as_float(u << 16); }
__device__ inline float bhi(uint32 u) { return __uint_as_float(u & 0xffff0000u); }
__device__ inline ushort16 f2b(float f) {
    uint32 u = __float_as_uint(f);
    u += 0x7fffu + ((u >> 16) & 1u);   // round-to-nearest-even
    return (ushort16)(u >> 16);
}
__device__ inline uint32 pack2(float lo, float hi) {
    return (uint32)f2b(lo) | ((uint32)f2b(hi) << 16);
}
__device__ inline float lrelu(float v) { return (v > 0.f) ? v : SLOPE * v; }
__device__ inline void addup(float* acc, uint4 u) {
    acc[0] += blo(u.x); acc[1] += bhi(u.x);
    acc[2] += blo(u.y); acc[3] += bhi(u.y);
    acc[4] += blo(u.z); acc[5] += bhi(u.z);
    acc[6] += blo(u.w); acc[7] += bhi(u.w);
}

// ---- prep: zero bhist + convert weights to bf16 [col][k] layouts ----
__global__ __launch_bounds__(256) void prep_kernel(
    const float* __restrict__ Wl1, const float* __restrict__ Wr1,
    const float* __restrict__ Wl2, const float* __restrict__ Wr2,
    ushort16* __restrict__ Wb1, ushort16* __restrict__ Wb2,
    int* __restrict__ bhist) {
    const int gid = blockIdx.x * 256 + threadIdx.x;
    if (gid < NBMAX) bhist[gid] = 0;
    for (int i = gid; i < 128 * 128; i += gridDim.x * 256) {
        int c = i >> 7, k = i & 127;
        Wb1[i] = f2b((c < HID) ? Wl1[k * HID + c] : Wr1[k * HID + (c - HID)]);
    }
    for (int i = gid; i < 64 * 64; i += gridDim.x * 256) {
        int c = i >> 6, k = i & 63;
        Wb2[i] = f2b((c < OUT_DIM) ? Wl2[k * OUT_DIM + c]
                                   : Wr2[k * OUT_DIM + (c - OUT_DIM)]);
    }
}

// ---- fused: MFMA gemm1 (blocks < ngemm) + bucket histogram (rest) ----
// gemm1: x[N,128] @ Wb1 -> xl bf16[N,64], xr fp32[N,64]+b1. A-tile-only LDS.
__global__ __launch_bounds__(256) void gemm1_hist_kernel(
    const float* __restrict__ x, const ushort16* __restrict__ Wb1,
    const float* __restrict__ b1,
    const int* __restrict__ dst, int* __restrict__ bhist,
    ushort16* __restrict__ xl, float* __restrict__ xr,
    int N, int E, int ngemm) {
    using frag = __attribute__((ext_vector_type(8))) short;
    using f32x4 = __attribute__((ext_vector_type(4))) float;
    constexpr int LDA = IN_DIM + 8;                 // 136 elems = 272 B (16B-mult)
    __shared__ ushort16 Ash[64][LDA];               // 17.4 KB
    const int tid = threadIdx.x;
    if (blockIdx.x >= ngemm) {                      // ---- histogram path ----
        int* bh = (int*)Ash;
        for (int i = tid; i < NBMAX; i += 256) bh[i] = 0;
        __syncthreads();
        const int b0 = blockIdx.x - ngemm;
        for (int e = b0 * 256 + tid; e < E; e += HIST_BLOCKS * 256)
            atomicAdd(&bh[dst[e] >> NPB_SHIFT], 1);
        __syncthreads();
        for (int b = tid; b < NBMAX; b += 256)
            if (bh[b]) atomicAdd(&bhist[b], bh[b]);
        return;
    }
    // ---- gemm path ----
    const int n0 = blockIdx.x * 64;
    {
        const int lc = (tid & 31) * 4;
        for (int row = tid >> 5; row < 64; row += 8) {
            int node = n0 + row;
            float4 xv = (node < N)
                ? *reinterpret_cast<const float4*>(&x[(long)node * IN_DIM + lc])
                : float4{0.f, 0.f, 0.f, 0.f};
            ushort16 pk[4] = {f2b(xv.x), f2b(xv.y), f2b(xv.z), f2b(xv.w)};
            *reinterpret_cast<ushort2*>(&Ash[row][lc])     = ushort2{pk[0], pk[1]};
            *reinterpret_cast<ushort2*>(&Ash[row][lc + 2]) = ushort2{pk[2], pk[3]};
        }
    }
    __syncthreads();
    const int lane = tid & 63;
    const int m0   = (tid >> 6) * 16;
    const int mlo  = lane & 15;
    const int qk   = lane >> 4;
    frag Af[4];
#pragma unroll
    for (int kc = 0; kc < 4; ++kc)
        Af[kc] = *reinterpret_cast<const frag*>(&Ash[m0 + mlo][kc * 32 + qk * 8]);
#pragma unroll
    for (int ct = 0; ct < 8; ++ct) {
        f32x4 acc = {0.f, 0.f, 0.f, 0.f};
#pragma unroll
        for (int kc = 0; kc < 4; ++kc) {
            frag Bf = *reinterpret_cast<const frag*>(
                &Wb1[(ct * 16 + mlo) * 128 + kc * 32 + qk * 8]);
            acc = __builtin_amdgcn_mfma_f32_16x16x32_bf16(Af[kc], Bf, acc, 0, 0, 0);
        }
        const int col = ct * 16 + mlo;
#pragma unroll
        for (int r = 0; r < 4; ++r) {
            int node = n0 + m0 + qk * 4 + r;
            if (node < N) {
                if (col < HID) xl[(long)node * HID + col] = f2b(acc[r]);
                else           xr[(long)node * HID + (col - HID)] = acc[r] + b1[col - HID];
            }
        }
    }
}

// ---- scan bucket sizes -> padded pair bases (1 block) ----
__global__ __launch_bounds__(512) void bucket_scan_kernel(
    const int* __restrict__ bhist, int* __restrict__ pbase,
    int* __restrict__ bcur, int NB) {
    __shared__ int s2[512];
    const int t = threadIdx.x;
    int bh = (t < NB) ? bhist[t] : 0;
    int pd = (bh + 15) & ~15;
    s2[t] = pd; __syncthreads();
    for (int off = 1; off < 512; off <<= 1) {
        int b = (t >= off) ? s2[t - off] : 0;
        __syncthreads();
        s2[t] += b;
        __syncthreads();
    }
    pbase[t] = s2[t] - pd;
    bcur[t]  = s2[t] - pd;
}

// ---- partition edges into bucket regions of pairs[] ----
// Flush via per-entry binary search -> coalesced global stores.
__global__ __launch_bounds__(256) void partition_kernel(
    const int* __restrict__ src, const int* __restrict__ dst,
    int* __restrict__ bcur, uint32* __restrict__ pairs, int E, int NB) {
    __shared__ int hist[NBMAX], loff[NBMAX], cur[NBMAX], gbase[NBMAX];
    __shared__ int s[256];
    __shared__ uint32 stage[CHUNK];
    const int tid = threadIdx.x;
    const int e0  = blockIdx.x * CHUNK;
    const int cnt = min(CHUNK, E - e0);
    for (int i = tid; i < NBMAX; i += 256) hist[i] = 0;
    __syncthreads();
    int sreg[16], dreg[16];
#pragma unroll
    for (int k = 0; k < 16; ++k) {
        int i = tid + k * 256;
        if (i < cnt) {
            sreg[k] = src[e0 + i];
            dreg[k] = dst[e0 + i];
            atomicAdd(&hist[dreg[k] >> NPB_SHIFT], 1);
        }
    }
    __syncthreads();
    int a0 = hist[2 * tid], a1 = hist[2 * tid + 1];
    s[tid] = a0 + a1; __syncthreads();
    for (int off = 1; off < 256; off <<= 1) {
        int t = (tid >= off) ? s[tid - off] : 0;
        __syncthreads();
        s[tid] += t;
        __syncthreads();
    }
    int ex = s[tid] - (a0 + a1);
    loff[2 * tid] = ex;      loff[2 * tid + 1] = ex + a0;
    cur[2 * tid]  = ex;      cur[2 * tid + 1]  = ex + a0;
    __syncthreads();
#pragma unroll
    for (int k = 0; k < 16; ++k) {
        int i = tid + k * 256;
        if (i < cnt) {
            int b = dreg[k] >> NPB_SHIFT;
            int pos = atomicAdd(&cur[b], 1);
            stage[pos] = (uint32)sreg[k] | ((uint32)(dreg[k] & 255) << 24);
        }
    }
    __syncthreads();
    for (int b = tid; b < NB; b += 256) {
        int cb = hist[b];
        if (cb) gbase[b] = atomicAdd(&bcur[b], cb);
    }
    __syncthreads();
    for (int i = tid; i < cnt; i += 256) {
        int lo = 0, hi = NB - 1;                     // invariant: loff[lo] <= i
        while (lo < hi) {
            int mid = (lo + hi + 1) >> 1;
            if (loff[mid] <= i) lo = mid; else hi = mid - 1;
        }
        pairs[gbase[lo] + (i - loff[lo])] = stage[i];
    }
}

// ---- agg1 + fine-bin fused: block = half-bucket (128 nodes), 512 threads ----
// Sorts the bucket's pairs in LDS (2 int LDS atomics/edge), emits CSR
// (srcs/rowptr/deg) for agg2, then h = LR(mean-gather(xl) + xr) -> bf16.
__global__ __launch_bounds__(512) void agg1_sort_kernel(
    const uint32* __restrict__ pairs, const int* __restrict__ bhist,
    const int* __restrict__ pbase,
    const uint4* __restrict__ xlq, const float* __restrict__ xr,
    uint32* __restrict__ srcs, int* __restrict__ rowptr, int* __restrict__ degA,
    uint4* __restrict__ hq, int N) {
    __shared__ int hist[256], loff[256], cur[128];
    __shared__ int lsrc[SUBCAP];
    const int tid  = threadIdx.x;
    const int bkt  = blockIdx.x >> 1;
    const int half = blockIdx.x & 1;
    const int n0   = bkt << NPB_SHIFT;
    const int base = pbase[bkt];
    const int sz   = bhist[bkt];
    if (tid < 256) hist[tid] = 0;
    __syncthreads();
    for (int i = tid; i < sz; i += 512)
        atomicAdd(&hist[pairs[base + i] >> 24], 1);
    __syncthreads();
    int v = (tid < 256) ? hist[tid] : 0;
    if (tid < 256) loff[tid] = v;
    __syncthreads();
    for (int off = 1; off < 256; off <<= 1) {
        int t = (tid >= off && tid < 256) ? loff[tid - off] : 0;
        __syncthreads();
        if (tid < 256) loff[tid] += t;
        __syncthreads();
    }
    if (tid < 256) loff[tid] -= v;                  // exclusive
    __syncthreads();
    if (half == 0 && tid < 256 && n0 + tid < N) {   // CSR for agg2
        rowptr[n0 + tid] = base + loff[tid];
        degA[n0 + tid]   = hist[tid];
    }
    const int hbase = loff[half << 7];
    const int hcnt  = (half ? sz : loff[128]) - hbase;
    if (tid < 128) cur[tid] = loff[(half << 7) + tid] - hbase;
    __syncthreads();
    for (int i = tid; i < sz; i += 512) {           // scatter my half into lsrc
        uint32 u = pairs[base + i];
        int dl = u >> 24;
        if ((dl >> 7) == half) {
            int pos = atomicAdd(&cur[dl & 127], 1);
            lsrc[pos] = (int)(u & 0xFFFFFFu);
        }
    }
    __syncthreads();
    for (int i = tid; i < hcnt; i += 512)           // coalesced CSR srcs
        srcs[base + hbase + i] = (uint32)lsrc[i];
    // ---- gather: 8 lanes/node, 8 nodes/wave, 2 passes of 64 nodes ----
    const int lane = tid & 63;
    const int wid  = tid >> 6;
    const int li   = lane & 7;
#pragma unroll
    for (int pass = 0; pass < 2; ++pass) {
        const int nl = (half << 7) + pass * 64 + wid * 8 + (lane >> 3);
        const int n  = n0 + nl;
        if (n >= N) continue;
        const int lo0 = loff[nl] - hbase;
        const int d   = hist[nl];
        float acc[8] = {};
        int j = 0;
        while (j + 16 <= d) {
            int i0[8], i1[8];
#pragma unroll
            for (int t = 0; t < 8; ++t) i0[t] = lsrc[lo0 + j + t];
#pragma unroll
            for (int t = 0; t < 8; ++t) i1[t] = lsrc[lo0 + j + 8 + t];
            uint4 u0[8], u1[8];
#pragma unroll
            for (int t = 0; t < 8; ++t) u0[t] = xlq[(long)i0[t] * 8 + li];
#pragma unroll
            for (int t = 0; t < 8; ++t) u1[t] = xlq[(long)i1[t] * 8 + li];
#pragma unroll
            for (int t = 0; t < 8; ++t) { addup(acc, u0[t]); addup(acc, u1[t]); }
            j += 16;
        }
        if (j + 8 <= d) {
            int i0[8];
#pragma unroll
            for (int t = 0; t < 8; ++t) i0[t] = lsrc[lo0 + j + t];
            uint4 u0[8];
#pragma unroll
            for (int t = 0; t < 8; ++t) u0[t] = xlq[(long)i0[t] * 8 + li];
#pragma unroll
            for (int t = 0; t < 8; ++t) addup(acc, u0[t]);
            j += 8;
        }
        for (; j < d; ++j) {
            uint4 u = xlq[(long)lsrc[lo0 + j] * 8 + li];
            addup(acc, u);
        }
        const float dinv = (d > 0) ? (1.f / (float)d) : 1.f;
        float4 xrA = *reinterpret_cast<const float4*>(&xr[(long)n * HID + 8 * li]);
        float4 xrB = *reinterpret_cast<const float4*>(&xr[(long)n * HID + 8 * li + 4]);
        float h[8];
        h[0] = fmaf(acc[0], dinv, xrA.x); h[1] = fmaf(acc[1], dinv, xrA.y);
        h[2] = fmaf(acc[2], dinv, xrA.z); h[3] = fmaf(acc[3], dinv, xrA.w);
        h[4] = fmaf(acc[4], dinv, xrB.x); h[5] = fmaf(acc[5], dinv, xrB.y);
        h[6] = fmaf(acc[6], dinv, xrB.z); h[7] = fmaf(acc[7], dinv, xrB.w);
#pragma unroll
        for (int t = 0; t < 8; ++t) h[t] = lrelu(h[t]);
        uint4 pk;
        pk.x = pack2(h[0], h[1]); pk.y = pack2(h[2], h[3]);
        pk.z = pack2(h[4], h[5]); pk.w = pack2(h[6], h[7]);
        hq[(long)n * 8 + li] = pk;
    }
}

// ---- MFMA gemm2: h bf16[N,64] @ Wb2 -> hl bf16[N,32], hr fp32[N,32]+b2 ----
// No LDS: A-frags from global h, B-frags from global Wb2 (L2-hot, 8 KB).
__global__ __launch_bounds__(256) void gemm2_mfma_kernel(
    const ushort16* __restrict__ hs, const ushort16* __restrict__ Wb2,
    const float* __restrict__ b2,
    ushort16* __restrict__ hl, float* __restrict__ hr, int N) {
    using frag = __attribute__((ext_vector_type(8))) short;
    using f32x4 = __attribute__((ext_vector_type(4))) float;
    const int tid  = threadIdx.x;
    const int n0   = blockIdx.x * 64;
    const int lane = tid & 63;
    const int m0   = (tid >> 6) * 16;
    const int mlo  = lane & 15;
    const int qk   = lane >> 4;
    const int row  = n0 + m0 + mlo;
    const int arow = (row < N) ? row : 0;
    frag Af[2];
#pragma unroll
    for (int kc = 0; kc < 2; ++kc)
        Af[kc] = *reinterpret_cast<const frag*>(&hs[(long)arow * HID + kc * 32 + qk * 8]);
#pragma unroll
    for (int ct = 0; ct < 4; ++ct) {
        f32x4 acc = {0.f, 0.f, 0.f, 0.f};
#pragma unroll
        for (int kc = 0; kc < 2; ++kc) {
            frag Bf = *reinterpret_cast<const frag*>(
                &Wb2[(ct * 16 + mlo) * 64 + kc * 32 + qk * 8]);
            acc = __builtin_amdgcn_mfma_f32_16x16x32_bf16(Af[kc], Bf, acc, 0, 0, 0);
        }
        const int col = ct * 16 + mlo;
#pragma unroll
        for (int r = 0; r < 4; ++r) {
            int node = n0 + m0 + qk * 4 + r;
            if (node < N) {
                if (col < OUT_DIM) hl[(long)node * OUT_DIM + col] = f2b(acc[r]);
                else hr[(long)node * OUT_DIM + (col - OUT_DIM)] = acc[r] + b2[col - OUT_DIM];
            }
        }
    }
}

// ---- agg2: z = LR(mean-gather(hl) + hr) ----
// 4 lanes/node, 16 nodes/wave, 16 gathers in flight. CSR from agg1_sort.
__global__ __launch_bounds__(256) void agg2_final_kernel(
    const int* __restrict__ rowptr, const int* __restrict__ degA,
    const uint32* __restrict__ srcs,
    const uint4* __restrict__ hlq, const float* __restrict__ hr,
    float* __restrict__ z, int N) {
    const int lane  = threadIdx.x & 63;
    const int li    = lane & 3;
    const int gbase = lane & 60;
    const int wave  = (blockIdx.x << 2) + (threadIdx.x >> 6);
    const int n     = wave * 16 + (lane >> 2);
    if (n >= N) return;
    const int rp = rowptr[n];
    const int d  = degA[n];
    float acc[8] = {};
    int j = 0;
    while (j + 16 <= d) {
        int sA = (int)srcs[rp + j + li];
        int sB = (int)srcs[rp + j + 4 + li];
        int sC = (int)srcs[rp + j + 8 + li];
        int sD = (int)srcs[rp + j + 12 + li];
        uint4 u[16];
#pragma unroll
        for (int t = 0; t < 4; ++t) u[t]      = hlq[(long)__shfl(sA, gbase + t) * 4 + li];
#pragma unroll
        for (int t = 0; t < 4; ++t) u[4 + t]  = hlq[(long)__shfl(sB, gbase + t) * 4 + li];
#pragma unroll
        for (int t = 0; t < 4; ++t) u[8 + t]  = hlq[(long)__shfl(sC, gbase + t) * 4 + li];
#pragma unroll
        for (int t = 0; t < 4; ++t) u[12 + t] = hlq[(long)__shfl(sD, gbase + t) * 4 + li];
#pragma unroll
        for (int t = 0; t < 16; ++t) addup(acc, u[t]);
        j += 16;
    }
    while (j + 4 <= d) {
        int sA = (int)srcs[rp + j + li];
        uint4 u[4];
#pragma unroll
        for (int t = 0; t < 4; ++t) u[t] = hlq[(long)__shfl(sA, gbase + t) * 4 + li];
#pragma unroll
        for (int t = 0; t < 4; ++t) addup(acc, u[t]);
        j += 4;
    }
    int r = d - j;                     // 0..3
    if (r > 0) {
        int sA = (int)srcs[rp + j + ((li < r) ? li : 0)];
#pragma unroll
        for (int t = 0; t < 3; ++t) {
            if (t < r) {
                uint4 u = hlq[(long)__shfl(sA, gbase + t) * 4 + li];
                addup(acc, u);
            }
        }
    }
    const float dinv = (d > 0) ? (1.f / (float)d) : 1.f;
    float4 hA = *reinterpret_cast<const float4*>(&hr[(long)n * OUT_DIM + 8 * li]);
    float4 hB = *reinterpret_cast<const float4*>(&hr[(long)n * OUT_DIM + 8 * li + 4]);
    float4 vA, vB;
    vA.x = lrelu(fmaf(acc[0], dinv, hA.x)); vA.y = lrelu(fmaf(acc[1], dinv, hA.y));
    vA.z = lrelu(fmaf(acc[2], dinv, hA.z)); vA.w = lrelu(fmaf(acc[3], dinv, hA.w));
    vB.x = lrelu(fmaf(acc[4], dinv, hB.x)); vB.y = lrelu(fmaf(acc[5], dinv, hB.y));
    vB.z = lrelu(fmaf(acc[6], dinv, hB.z)); vB.w = lrelu(fmaf(acc[7], dinv, hB.w));
    *reinterpret_cast<float4*>(&z[(long)n * OUT_DIM + 8 * li]) = vA;
    *reinterpret_cast<float4*>(&z[(long)n * OUT_DIM + 8 * li + 4]) = vB;
}

extern "C" void kernel_launch(void* const* d_in, const int* in_sizes, int n_in,
                              void* d_out, int out_size, void* d_ws, size_t ws_size,
                              hipStream_t stream) {
    const float* x   = (const float*)d_in[0];
    const int*   ei  = (const int*)d_in[1];
    const float* Wl1 = (const float*)d_in[2];
    const float* Wr1 = (const float*)d_in[3];
    const float* b1  = (const float*)d_in[4];
    const float* Wl2 = (const float*)d_in[5];
    const float* Wr2 = (const float*)d_in[6];
    const float* b2  = (const float*)d_in[7];

    const int N = in_sizes[0] / IN_DIM;
    const int E = in_sizes[1] / 2;
    const int* src = ei;
    const int* dst = ei + E;
    const int NB = (N + 255) >> NPB_SHIFT;   // buckets (<= 512)

    char* p = (char*)d_ws;
    int* bhist    = (int*)p;           p += sizeof(int) * NBMAX;
    int* pbase    = (int*)p;           p += sizeof(int) * NBMAX;
    int* bcur     = (int*)p;           p += sizeof(int) * NBMAX;
    int* rowptr   = (int*)p;           p += sizeof(int) * (N + 4);
    int* degA     = (int*)p;           p += sizeof(int) * (N + 4);
    uint32* pairs = (uint32*)p;        p += sizeof(uint32) * ((size_t)E + 16 * NBMAX);
    uint32* srcs  = (uint32*)p;        p += sizeof(uint32) * ((size_t)E + 16 * NBMAX);
    ushort16* Wb1 = (ushort16*)p;      p += sizeof(ushort16) * 128 * 128;
    ushort16* Wb2 = (ushort16*)p;      p += sizeof(ushort16) * 64 * 64;
    ushort16* xl  = (ushort16*)p;      p += sizeof(ushort16) * (size_t)N * HID;
    float* xr     = (float*)p;         p += sizeof(float) * (size_t)N * HID;
    ushort16* h   = (ushort16*)p;      p += sizeof(ushort16) * (size_t)N * HID;
    ushort16* hl  = (ushort16*)p;      p += sizeof(ushort16) * (size_t)N * OUT_DIM;
    float* hr     = (float*)p;         p += sizeof(float) * (size_t)N * OUT_DIM;

    const int ngemm = (N + 63) / 64;
    prep_kernel<<<32, 256, 0, stream>>>(Wl1, Wr1, Wl2, Wr2, Wb1, Wb2, bhist);
    gemm1_hist_kernel<<<ngemm + HIST_BLOCKS, 256, 0, stream>>>(
        x, Wb1, b1, dst, bhist, xl, xr, N, E, ngemm);
    bucket_scan_kernel<<<1, 512, 0, stream>>>(bhist, pbase, bcur, NB);
    partition_kernel<<<(E + CHUNK - 1) / CHUNK, 256, 0, stream>>>(src, dst, bcur, pairs, E, NB);
    agg1_sort_kernel<<<NB * 2, 512, 0, stream>>>(pairs, bhist, pbase,
                                                 (const uint4*)xl, xr,
                                                 srcs, rowptr, degA, (uint4*)h, N);
    gemm2_mfma_kernel<<<(N + 63) / 64, 256, 0, stream>>>(h, Wb2, b2, hl, hr, N);
    agg2_final_kernel<<<(N + 63) / 64, 256, 0, stream>>>(rowptr, degA, srcs,
                                                         (const uint4*)hl, hr,
                                                         (float*)d_out, N);
}